// Round 17
// baseline (447.875 us; speedup 1.0000x reference)
//
#include <hip/hip_runtime.h>
#include <hip/hip_bf16.h>
#include <math.h>

// Problem constants
constexpr int kD   = 256;
constexpr int kH   = 4;
constexpr int kHD  = 64;
constexpr int kB   = 2;
constexpr int kN   = 6;
constexpr int kM   = 512;
constexpr int kRowsH = kB*kN*kM;          // 6144
constexpr int kRows  = 2*kRowsH;          // 12288
constexpr int kGrpH  = kB*kN*kH;          // 48
constexpr int kGrp   = 2*kGrpH;           // 96
constexpr size_t kTOK = (size_t)kRowsH*kD;        // 1,572,864
constexpr size_t kEncSlab = (size_t)kN*kM*kHD;    // 196608
constexpr size_t kQEncSlab = (size_t)kN*kN*kHD;   // 2304
constexpr float kL2E = 1.4426950408889634f;

typedef unsigned short u16;
typedef __attribute__((ext_vector_type(8))) short s16x8;
typedef __attribute__((ext_vector_type(4))) float f32x4;

__device__ __forceinline__ float wred_sum(float v){
  #pragma unroll
  for (int m=32;m>0;m>>=1) v += __shfl_xor(v, m, 64);
  return v;
}
__device__ __forceinline__ u16 f2b(float x){
  union { float f; unsigned u; } a; a.f = x;
  unsigned r = a.u + 0x7fffu + ((a.u >> 16) & 1u);
  return (u16)(r >> 16);
}
__device__ __forceinline__ float b2f(u16 x){
  union { unsigned u; float f; } a; a.u = ((unsigned)x) << 16;
  return a.f;
}
__device__ __forceinline__ unsigned pk2(float lo, float hi){
  union { __hip_bfloat162 h2; unsigned u; } c;
  c.h2 = __float22bfloat162_rn(make_float2(lo, hi));
  return c.u;
}

// ---------------------------------------------------------------------------
// FFN out-proj fusion precompute: W' = Wout @ W1_bot, b1' = b1 + bout @ W1_bot
// Blocks [0,128): W' tiles. Blocks [128,136): fused biases.
// ---------------------------------------------------------------------------
struct FuseArgs {
  const float* Wout[4]; const float* W1[4];
  const float* bout[4]; const float* b1[4];
  float* Wtmp; float* b1p;
};

__global__ __launch_bounds__(256) void wfuse_k(FuseArgs fa)
{
  if (blockIdx.x >= 128) {
    const int bb = blockIdx.x - 128;
    const int set = bb >> 1;
    const int n = (bb & 1)*256 + threadIdx.x;
    const float* W1 = fa.W1[set];
    const float* bo = fa.bout[set];
    float s = fa.b1[set][n];
    for (int k = 0; k < 256; ++k)
      s = fmaf(bo[k], W1[(size_t)(256+k)*512 + n], s);
    fa.b1p[set*512 + n] = s;
    return;
  }
  const int set = blockIdx.x >> 5;
  const int t = blockIdx.x & 31;
  const int row0 = (t >> 3)*64, col0 = (t & 7)*64;
  const float* A  = fa.Wout[set];            // 256x256
  const float* Bm = fa.W1[set] + 256*512;    // rows 256..511, ld 512
  float* C = fa.Wtmp + (size_t)set*(256*512);
  __shared__ float As[16][65];
  __shared__ float Bs[16][64];
  const int tid = threadIdx.x;
  const int tx = tid & 15, ty = tid >> 4;
  const int ar = tid >> 2, ak = (tid & 3)*4;
  const int wr = tid >> 4, wc = (tid & 15)*4;
  float acc[4][4] = {};
  for (int kt = 0; kt < 256; kt += 16) {
    float4 av = *(const float4*)(A + (size_t)(row0+ar)*256 + kt + ak);
    As[ak+0][ar]=av.x; As[ak+1][ar]=av.y; As[ak+2][ar]=av.z; As[ak+3][ar]=av.w;
    *(float4*)(&Bs[wr][wc]) = *(const float4*)(Bm + (size_t)(kt+wr)*512 + col0 + wc);
    __syncthreads();
    #pragma unroll
    for (int k2=0;k2<16;++k2) {
      float a[4], b[4];
      #pragma unroll
      for (int i=0;i<4;++i) a[i]=As[k2][ty*4+i];
      #pragma unroll
      for (int j=0;j<4;++j) b[j]=Bs[k2][tx*4+j];
      #pragma unroll
      for (int i=0;i<4;++i)
        #pragma unroll
        for (int j=0;j<4;++j) acc[i][j] = fmaf(a[i], b[j], acc[i][j]);
    }
    __syncthreads();
  }
  #pragma unroll
  for (int i=0;i<4;++i)
    #pragma unroll
    for (int j=0;j<4;++j)
      C[(size_t)(row0+ty*4+i)*512 + col0+tx*4+j] = acc[i][j];
}

// ---------------------------------------------------------------------------
// Weight cast into GEMM staging-tile image (Bs LDS image, swizzle baked in).
// ---------------------------------------------------------------------------
struct WtDesc { const float* W; const float* W2; u16* Wt; int K; int N; int ntiles; };
struct WtTable { WtDesc d[18]; };

__global__ __launch_bounds__(256) void wtcast_k(WtTable tab)
{
  int t = blockIdx.x, mi = 0;
  while (t >= tab.d[mi].ntiles) { t -= tab.d[mi].ntiles; ++mi; }
  const float* W = tab.d[mi].W;
  const float* W2 = tab.d[mi].W2;
  u16* Wt = tab.d[mi].Wt;
  const int K = tab.d[mi].K, N = tab.d[mi].N;
  const int ktn = K >> 5;
  const int nt = t / ktn, kt = t % ktn;
  const int n0 = nt*128, k0 = kt*32;
  u16* dst = Wt + (size_t)t*4096;
  #pragma unroll
  for (int s = 0; s < 2; ++s) {
    const int idx0 = (s*256 + (int)threadIdx.x)*8;
    const int ar = idx0 >> 5;
    const int w8 = (idx0 >> 3) & 3;
    const int sw = (ar >> 1) & 3;
    int kk = k0 + ((w8 ^ sw) << 3);
    const int n  = n0 + ar;
    const float* src = W;
    if (W2 && kk >= 256) { src = W2; kk -= 256; }
    union { u16 u[8]; s16x8 v; } o;
    #pragma unroll
    for (int e = 0; e < 8; ++e)
      o.u[e] = f2b(src[(size_t)(kk + e)*N + n]);
    *(s16x8*)(dst + idx0) = o.v;
  }
}

// ---------------------------------------------------------------------------
// bf16 MFMA GEMM, dual row-segment + dual col-segment bias. 2-phase
// double-buffered LDS. XCD-bijective block swizzle.
// ---------------------------------------------------------------------------
template<bool A1B, bool A2B, bool CB>
__global__ __launch_bounds__(256) void mmad_k(
    const void* __restrict__ A1a, const void* __restrict__ A1b,
    const void* __restrict__ A2a, const void* __restrict__ A2b, int K1,
    const u16* __restrict__ Wa, const u16* __restrict__ Wb,
    const float* __restrict__ bia, const float* __restrict__ bib,
    const float* __restrict__ bi2a, const float* __restrict__ bi2b, int Ns,
    const float* __restrict__ Ra, const float* __restrict__ Rb,
    void* __restrict__ Cp, int N, int K, int Mh, int doRelu)
{
  __shared__ u16 As[2][128*32];
  __shared__ u16 Bs[2][128*32];
  const int tid = threadIdx.x;
  const int lane = tid & 63, w = tid >> 6;
  const int gx = gridDim.x;
  const int nblk = gx * gridDim.y;
  int flat = blockIdx.y*gx + blockIdx.x;
  if (!(nblk & 7)) flat = (flat & 7)*(nblk >> 3) + (flat >> 3);
  const int bxx = flat % gx, byy = flat / gx;
  const int row0 = byy*128, col0 = bxx*128;
  const bool sec = (row0 >= Mh);
  const int lr0 = sec ? row0 - Mh : row0;
  const void* A1 = sec ? A1b : A1a;
  const void* A2 = sec ? A2b : A2a;
  const u16* Wt  = sec ? Wb : Wa;
  const float* bias  = sec ? bib : bia;
  const float* bias2 = sec ? bi2b : bi2a;
  const float* R = sec ? Rb : Ra;
  const int wr = (w >> 1)*64, wc = (w & 1)*64;
  const int ar = tid >> 1, ah = tid & 1;
  const int K2 = K - K1;
  const int ktn = K >> 5;
  f32x4 acc[4][4] = {};

  auto stage = [&](int buf, int kt) {
    const u16* wtile = Wt + ((size_t)((col0 >> 7)*ktn + (kt >> 5)))*4096;
    #pragma unroll
    for (int s = 0; s < 2; ++s) {
      const u16* srcp = wtile + (size_t)(s*256 + tid)*8;
      __builtin_amdgcn_global_load_lds(
          (const __attribute__((address_space(1))) void*)srcp,
          (__attribute__((address_space(3))) void*)((char*)Bs[buf] + s*4096 + w*1024),
          16, 0, 0);
    }
    const int kk = kt + ah*16;
    union { u16 u[16]; s16x8 v[2]; } tmp;
    if (kk < K1) {
      if constexpr (A1B) {
        const u16* ap = (const u16*)A1 + (size_t)(lr0+ar)*K1 + kk;
        tmp.v[0] = *(const s16x8*)ap; tmp.v[1] = *(const s16x8*)(ap+8);
      } else {
        const float* ap = (const float*)A1 + (size_t)(lr0+ar)*K1 + kk;
        #pragma unroll
        for (int i = 0; i < 16; i += 4) {
          f32x4 v4 = *(const f32x4*)(ap + i);
          tmp.u[i+0]=f2b(v4.x); tmp.u[i+1]=f2b(v4.y); tmp.u[i+2]=f2b(v4.z); tmp.u[i+3]=f2b(v4.w);
        }
      }
    } else {
      if constexpr (A2B) {
        const u16* ap = (const u16*)A2 + (size_t)(lr0+ar)*K2 + (kk - K1);
        tmp.v[0] = *(const s16x8*)ap; tmp.v[1] = *(const s16x8*)(ap+8);
      } else {
        const float* ap = (const float*)A2 + (size_t)(lr0+ar)*K2 + (kk - K1);
        #pragma unroll
        for (int i = 0; i < 16; i += 4) {
          f32x4 v4 = *(const f32x4*)(ap + i);
          tmp.u[i+0]=f2b(v4.x); tmp.u[i+1]=f2b(v4.y); tmp.u[i+2]=f2b(v4.z); tmp.u[i+3]=f2b(v4.w);
        }
      }
    }
    const int sw = (ar >> 1) & 3;
    *(s16x8*)(&As[buf][ar*32 + ((ah*2+0)^sw)*8]) = tmp.v[0];
    *(s16x8*)(&As[buf][ar*32 + ((ah*2+1)^sw)*8]) = tmp.v[1];
  };

  stage(0, 0);
  __syncthreads();
  for (int t = 0; t < ktn; ++t) {
    const int cur = t & 1;
    if (t + 1 < ktn) stage(cur ^ 1, (t + 1) << 5);
    s16x8 af[4], bfv[4];
    #pragma unroll
    for (int fm = 0; fm < 4; ++fm) {
      const int r = wr + fm*16 + (lane & 15);
      const int g = (lane >> 4) ^ ((r >> 1) & 3);
      af[fm] = *(const s16x8*)(&As[cur][r*32 + g*8]);
    }
    #pragma unroll
    for (int fn = 0; fn < 4; ++fn) {
      const int c = wc + fn*16 + (lane & 15);
      const int g = (lane >> 4) ^ ((c >> 1) & 3);
      bfv[fn] = *(const s16x8*)(&Bs[cur][c*32 + g*8]);
    }
    #pragma unroll
    for (int fm = 0; fm < 4; ++fm)
      #pragma unroll
      for (int fn = 0; fn < 4; ++fn)
        acc[fm][fn] = __builtin_amdgcn_mfma_f32_16x16x32_bf16(af[fm], bfv[fn], acc[fm][fn], 0, 0, 0);
    __syncthreads();
  }

  #pragma unroll
  for (int fm = 0; fm < 4; ++fm) {
    const int ro = wr + fm*16 + (lane >> 4)*4;
    #pragma unroll
    for (int fn = 0; fn < 4; ++fn) {
      const int cc = col0 + wc + fn*16 + (lane & 15);
      const float bv = (cc < Ns) ? bias[cc] : bias2[cc - Ns];
      #pragma unroll
      for (int j = 0; j < 4; ++j) {
        float v = acc[fm][fn][j] + bv;
        if (R) v += R[(size_t)(lr0 + ro + j)*N + cc];
        if (doRelu) v = fmaxf(v, 0.f);
        const size_t idx = (size_t)(row0 + ro + j)*N + cc;
        if constexpr (CB) ((u16*)Cp)[idx] = f2b(v);
        else              ((float*)Cp)[idx] = v;
      }
    }
  }
}

// ---------------------------------------------------------------------------
// Preps (read bf16 qkv/kv): emit bf16 K [g][key][64], bf16 Vt [g][64][key],
// and Q (self: roped+0.125-prescaled bf16; s2s: raw f32; cross: K prescaled).
// ---------------------------------------------------------------------------
__global__ __launch_bounds__(256) void prep_self_k(
    const u16* __restrict__ qkvU, const float* __restrict__ t_enc,
    const float* __restrict__ s_enc,
    u16* __restrict__ Qb, u16* __restrict__ Kb, u16* __restrict__ Vt)
{
  __shared__ u16 vs[64][66];
  const int g = blockIdx.x >> 3, i0 = (blockIdx.x & 7)*64;
  const int h = g & 3, bn = g >> 2;
  const float* enc = (bn < 12) ? t_enc : s_enc;
  const int n = (bn < 12 ? bn : bn - 12) % kN;
  const int c = threadIdx.x & 63, t4 = threadIdx.x >> 6;
  const float sgn = (c & 1) ? 1.f : -1.f;
  #pragma unroll 4
  for (int rr = 0; rr < 16; ++rr) {
    const int il = rr*4 + t4, i = i0 + il;
    const u16* base = qkvU + ((size_t)bn*kM + i)*768 + h*192;
    const float q = b2f(base[c*3]), k = b2f(base[c*3+1]);
    const float qp = b2f(base[(c^1)*3]), kp = b2f(base[(c^1)*3+1]);
    const size_t eo = ((size_t)(n*kM + i))*kHD + c;
    const float e0 = enc[eo], e1 = enc[kEncSlab + eo];
    Qb[((size_t)g*kM + i)*kHD + c] = f2b((q*e0 + sgn*qp*e1)*0.125f);
    Kb[((size_t)g*kM + i)*kHD + c] = f2b(k*e0 + sgn*kp*e1);
    vs[il][c] = base[c*3+2];
  }
  __syncthreads();
  #pragma unroll 4
  for (int rr = 0; rr < 16; ++rr) {
    const int cc = rr*4 + t4;
    Vt[((size_t)g*kHD + cc)*kM + i0 + c] = vs[c][cc];
  }
}

__global__ __launch_bounds__(256) void prep_s2s_k(
    const u16* __restrict__ qkvU, const float* __restrict__ kenc,
    float* __restrict__ Qs, u16* __restrict__ Kb, u16* __restrict__ Vt)
{
  __shared__ u16 vs[64][66];
  const int g = blockIdx.x >> 3, i0 = (blockIdx.x & 7)*64;   // g = bh*6+view
  const int view = g % kN, bh = g / kN;
  const int h = bh & 3, b = bh >> 2;
  const int c = threadIdx.x & 63, t4 = threadIdx.x >> 6;
  const float sgn = (c & 1) ? 1.f : -1.f;
  #pragma unroll 4
  for (int rr = 0; rr < 16; ++rr) {
    const int il = rr*4 + t4, i = i0 + il;
    const u16* base = qkvU + ((size_t)(kRowsH + (b*kN+view)*kM + i))*768 + h*192;
    const float k = b2f(base[c*3+1]), kp = b2f(base[(c^1)*3+1]);
    const size_t eo = ((size_t)(view*kM + i))*kHD + c;
    const float e0 = kenc[eo], e1 = kenc[kEncSlab + eo];
    Qs[((size_t)g*kM + i)*kHD + c] = b2f(base[c*3]);
    Kb[((size_t)g*kM + i)*kHD + c] = f2b(k*e0 + sgn*kp*e1);
    vs[il][c] = base[c*3+2];
  }
  __syncthreads();
  #pragma unroll 4
  for (int rr = 0; rr < 16; ++rr) {
    const int cc = rr*4 + t4;
    Vt[((size_t)g*kHD + cc)*kM + i0 + c] = vs[c][cc];
  }
}

__global__ __launch_bounds__(256) void prep_cross_k(
    const u16* __restrict__ qkvC, u16* __restrict__ Kb, u16* __restrict__ Vt)
{
  __shared__ u16 vs[64][66];
  const int g = blockIdx.x >> 3, i0 = (blockIdx.x & 7)*64;
  const int h = g & 3, bn = g >> 2;
  const int src = (bn < 12) ? bn + 12 : bn - 12;
  const int c = threadIdx.x & 63, t4 = threadIdx.x >> 6;
  #pragma unroll 4
  for (int rr = 0; rr < 16; ++rr) {
    const int il = rr*4 + t4, i = i0 + il;
    const u16* base = qkvC + ((size_t)src*kM + i)*768 + 256 + h*128;
    Kb[((size_t)g*kM + i)*kHD + c] = f2b(b2f(base[c*2]) * 0.125f);
    vs[il][c] = base[c*2+1];
  }
  __syncthreads();
  #pragma unroll 4
  for (int rr = 0; rr < 16; ++rr) {
    const int cc = rr*4 + t4;
    Vt[((size_t)g*kHD + cc)*kM + i0 + c] = vs[c][cc];
  }
}

// ---------------------------------------------------------------------------
// self/cross attention: 64 q-rows/wave (4 fragments sharing all K/V loads),
// online softmax + defer-max with shfl-free guard; E/F/G/H redistribution.
// 192 blocks (8 XCD chunks x 24): g = bij>>1, qblk = bij&1.
// ---------------------------------------------------------------------------
template<int CROSSQ>
__global__ __launch_bounds__(256) void attn_mm_k(
    const u16* __restrict__ Qb, const u16* __restrict__ Kb,
    const u16* __restrict__ Vt, u16* __restrict__ ctx)
{
  const int w = threadIdx.x >> 6, lane = threadIdx.x & 63;
  const int bij = (blockIdx.x & 7)*24 + (blockIdx.x >> 3);   // 192
  const int g = bij >> 1, qblk = bij & 1;
  const int h = g & 3, bn = g >> 2;
  const int q0 = qblk*256 + w*64;
  const int qr = lane & 15, hi = lane >> 4;
  const bool subhi = (hi & 1), up = (hi >= 2);

  s16x8 qf0[4], qf1[4];
  #pragma unroll
  for (int f = 0; f < 4; ++f) {
    const u16* qp = CROSSQ
      ? Qb + ((size_t)(bn*kM + q0 + f*16 + qr))*768 + h*kHD + hi*8
      : Qb + ((size_t)g*kM + q0 + f*16 + qr)*kHD + hi*8;
    qf0[f] = *(const s16x8*)(qp);
    qf1[f] = *(const s16x8*)(qp + 32);
  }

  const u16* Kg = Kb + (size_t)g*kM*kHD;
  const u16* Vg = Vt + (size_t)g*kHD*kM;
  f32x4 acc[4][4] = {};
  float m[4] = {-1e30f, -1e30f, -1e30f, -1e30f}, l[4] = {0.f, 0.f, 0.f, 0.f};

  for (int kc = 0; kc < 16; ++kc) {
    const int k0 = kc*32;
    s16x8 a0[2], a1[2];
    #pragma unroll
    for (int t = 0; t < 2; ++t) {
      const u16* kp = Kg + ((size_t)(k0 + t*16 + qr))*kHD + hi*8;
      a0[t] = *(const s16x8*)(kp);
      a1[t] = *(const s16x8*)(kp + 32);
    }
    s16x8 pa[4];
    #pragma unroll
    for (int f = 0; f < 4; ++f) {
      f32x4 st[2];
      #pragma unroll
      for (int t = 0; t < 2; ++t) {
        f32x4 z = {0.f, 0.f, 0.f, 0.f};
        z = __builtin_amdgcn_mfma_f32_16x16x32_bf16(a0[t], qf0[f], z, 0, 0, 0);
        z = __builtin_amdgcn_mfma_f32_16x16x32_bf16(a1[t], qf1[f], z, 0, 0, 0);
        st[t] = z;
      }
      float mloc = fmaxf(fmaxf(fmaxf(st[0][0], st[0][1]), fmaxf(st[0][2], st[0][3])),
                         fmaxf(fmaxf(st[1][0], st[1][1]), fmaxf(st[1][2], st[1][3])));
      if (!__all(mloc - m[f] <= 8.f)) {
        mloc = fmaxf(mloc, __shfl_xor(mloc, 16));
        mloc = fmaxf(mloc, __shfl_xor(mloc, 32));
        const float mn = fmaxf(m[f], mloc);
        const float r = exp2f((m[f] - mn)*kL2E);
        m[f] = mn;
        l[f] *= r;
        const float rr0 = __shfl(r, hi*4+0), rr1 = __shfl(r, hi*4+1);
        const float rr2 = __shfl(r, hi*4+2), rr3 = __shfl(r, hi*4+3);
        #pragma unroll
        for (int db = 0; db < 4; ++db) {
          acc[f][db][0] *= rr0; acc[f][db][1] *= rr1;
          acc[f][db][2] *= rr2; acc[f][db][3] *= rr3;
        }
      }
      float p[8], ls = 0.f;
      #pragma unroll
      for (int t = 0; t < 2; ++t)
        #pragma unroll
        for (int j = 0; j < 4; ++j) {
          const float pv = exp2f((st[t][j] - m[f])*kL2E);
          p[t*4+j] = pv; ls += pv;
        }
      l[f] += ls;
      const unsigned c00 = pk2(p[0], p[1]);
      const unsigned c01 = pk2(p[2], p[3]);
      const unsigned c10 = pk2(p[4], p[5]);
      const unsigned c11 = pk2(p[6], p[7]);
      const unsigned c00x = __shfl_xor((int)c00, 32), c10x = __shfl_xor((int)c10, 32);
      const unsigned c01x = __shfl_xor((int)c01, 32), c11x = __shfl_xor((int)c11, 32);
      const unsigned E = up ? c10x : c00, F = up ? c10 : c00x;
      const unsigned G = up ? c11x : c01, H = up ? c11 : c01x;
      const unsigned Ex = __shfl_xor((int)E, 16), Fx = __shfl_xor((int)F, 16);
      const unsigned Gx = __shfl_xor((int)G, 16), Hx = __shfl_xor((int)H, 16);
      union { unsigned w[4]; s16x8 v; } pw;
      pw.w[0] = subhi ? Fx : E;
      pw.w[1] = subhi ? Hx : G;
      pw.w[2] = subhi ? F  : Ex;
      pw.w[3] = subhi ? H  : Gx;
      pa[f] = pw.v;
    }
    #pragma unroll
    for (int db = 0; db < 4; ++db) {
      const s16x8 vf = *(const s16x8*)(Vg + ((size_t)(db*16 + qr))*kM + k0 + hi*8);
      #pragma unroll
      for (int f = 0; f < 4; ++f)
        acc[f][db] = __builtin_amdgcn_mfma_f32_16x16x32_bf16(pa[f], vf, acc[f][db], 0, 0, 0);
    }
  }

  #pragma unroll
  for (int f = 0; f < 4; ++f) {
    float lf = l[f];
    lf += __shfl_xor(lf, 16); lf += __shfl_xor(lf, 32);
    const float li = 1.f/lf;
    const float l0 = __shfl(li, hi*4+0), l1 = __shfl(li, hi*4+1);
    const float l2 = __shfl(li, hi*4+2), l3 = __shfl(li, hi*4+3);
    #pragma unroll
    for (int db = 0; db < 4; ++db) {
      const size_t base = ((size_t)(bn*kM + q0 + f*16 + hi*4))*kD + h*kHD + db*16 + qr;
      ctx[base + 0*kD] = f2b(acc[f][db][0]*l0);
      ctx[base + 1*kD] = f2b(acc[f][db][1]*l1);
      ctx[base + 2*kD] = f2b(acc[f][db][2]*l2);
      ctx[base + 3*kD] = f2b(acc[f][db][3]*l3);
    }
  }
}

__device__ __forceinline__ void rope4(const f32x4 x, const f32x4 e0, const f32x4 e1, float o[4])
{
  o[0] = x[0]*e0[0] - x[1]*e1[0];
  o[1] = x[1]*e0[1] + x[0]*e1[1];
  o[2] = x[2]*e0[2] - x[3]*e1[2];
  o[3] = x[3]*e0[3] + x[2]*e1[3];
}

// ---------------------------------------------------------------------------
// FAT kernel: blocks [0,480) = s2s attention (64 q-rows/wave: 4 fragments
// sharing all K/V loads); blocks [480, 480+6144) = t2t attention.
// ---------------------------------------------------------------------------
__global__ __launch_bounds__(256) void attn_comb_k(
    const float* __restrict__ Qraw, const u16* __restrict__ Kb,
    const u16* __restrict__ Vt, const float* __restrict__ qenc,
    u16* __restrict__ ctx5, const u16* __restrict__ qkvU,
    u16* __restrict__ ctxU)
{
  if (blockIdx.x >= 480) {
    // ---- t2t ----
    const int wid = (blockIdx.x - 480)*4 + ((int)threadIdx.x >> 6);
    const int lane = threadIdx.x & 63;
    const int mm2 = wid & 511;
    const int t = wid >> 9;
    const int nq = t % kN;
    const int bh2 = t / kN;
    const int h2 = bh2 & 3, b2 = bh2 >> 2;
    const u16* pb[kN];
    #pragma unroll
    for (int nk = 0; nk < kN; ++nk)
      pb[nk] = qkvU + ((size_t)(b2*kN+nk)*kM + mm2)*768 + h2*192;
    const float qc = b2f(pb[nq][lane*3]);
    float sim[kN];
    #pragma unroll
    for (int nk = 0; nk < kN; ++nk)
      sim[nk] = wred_sum(qc * b2f(pb[nk][lane*3+1])) * 0.125f;
    float mx = sim[0];
    #pragma unroll
    for (int nk = 1; nk < kN; ++nk) mx = fmaxf(mx, sim[nk]);
    float p[kN], s = 0.f;
    #pragma unroll
    for (int nk = 0; nk < kN; ++nk) { p[nk] = expf(sim[nk]-mx); s += p[nk]; }
    const float inv = 1.f/s;
    float o = 0.f;
    #pragma unroll
    for (int nk = 0; nk < kN; ++nk) o = fmaf(p[nk], b2f(pb[nk][lane*3+2]), o);
    ctxU[((size_t)(b2*kN+nq)*kM + mm2)*kD + h2*kHD + lane] = f2b(o*inv);
    return;
  }
  // ---- s2s: 4 fragments (64 q-rows) per wave ----
  const int w = threadIdx.x >> 6, lane = threadIdx.x & 63;
  const int bij = (blockIdx.x & 7)*60 + (blockIdx.x >> 3);  // 480; chunk == bh
  const int bh = bij / 60;
  const int rest = bij % 60;
  const int col = rest / 10;
  const int rem = rest % 10;
  const int qblk = rem / 5, split = rem % 5;
  const int q0 = qblk*256 + w*64;
  const int qr = lane & 15, hi = lane >> 4;
  const bool subhi = (hi & 1), up = (hi >= 2);

  const int e  = split*6 + col;
  const int iv = e/5;
  const int j0 = e%5;
  const int jv = j0 + (j0 >= iv ? 1 : 0);

  s16x8 qf0[4], qf1[4];
  #pragma unroll
  for (int f = 0; f < 4; ++f) {
    const float* qp = Qraw + ((size_t)(bh*kN + jv)*kM + q0 + f*16 + qr)*kHD + hi*8;
    const float* ep = qenc + ((size_t)(iv*kN + jv))*kHD + hi*8;
    union { u16 u[8]; s16x8 v; } A, B;
    float o[4];
    rope4(*(const f32x4*)(qp),   *(const f32x4*)(ep),   *(const f32x4*)(ep+kQEncSlab), o);
    #pragma unroll
    for (int j = 0; j < 4; ++j) A.u[j] = f2b(o[j]*0.125f);
    rope4(*(const f32x4*)(qp+4), *(const f32x4*)(ep+4), *(const f32x4*)(ep+kQEncSlab+4), o);
    #pragma unroll
    for (int j = 0; j < 4; ++j) A.u[4+j] = f2b(o[j]*0.125f);
    rope4(*(const f32x4*)(qp+32), *(const f32x4*)(ep+32), *(const f32x4*)(ep+kQEncSlab+32), o);
    #pragma unroll
    for (int j = 0; j < 4; ++j) B.u[j] = f2b(o[j]*0.125f);
    rope4(*(const f32x4*)(qp+36), *(const f32x4*)(ep+36), *(const f32x4*)(ep+kQEncSlab+36), o);
    #pragma unroll
    for (int j = 0; j < 4; ++j) B.u[4+j] = f2b(o[j]*0.125f);
    qf0[f] = A.v; qf1[f] = B.v;
  }

  const int g2 = bh*kN + iv;
  const u16* Kg = Kb + (size_t)g2*kM*kHD;
  const u16* Vg = Vt + (size_t)g2*kHD*kM;
  f32x4 acc[4][4] = {};
  float m[4] = {-1e30f, -1e30f, -1e30f, -1e30f}, l[4] = {0.f, 0.f, 0.f, 0.f};

  for (int kc = 0; kc < 16; ++kc) {
    const int k0 = kc*32;
    s16x8 a0[2], a1[2];
    #pragma unroll
    for (int t = 0; t < 2; ++t) {
      const u16* kp = Kg + ((size_t)(k0 + t*16 + qr))*kHD + hi*8;
      a0[t] = *(const s16x8*)(kp);
      a1[t] = *(const s16x8*)(kp + 32);
    }
    s16x8 pa[4];
    #pragma unroll
    for (int f = 0; f < 4; ++f) {
      f32x4 st[2];
      #pragma unroll
      for (int t = 0; t < 2; ++t) {
        f32x4 z = {0.f, 0.f, 0.f, 0.f};
        z = __builtin_amdgcn_mfma_f32_16x16x32_bf16(a0[t], qf0[f], z, 0, 0, 0);
        z = __builtin_amdgcn_mfma_f32_16x16x32_bf16(a1[t], qf1[f], z, 0, 0, 0);
        st[t] = z;
      }
      float mloc = fmaxf(fmaxf(fmaxf(st[0][0], st[0][1]), fmaxf(st[0][2], st[0][3])),
                         fmaxf(fmaxf(st[1][0], st[1][1]), fmaxf(st[1][2], st[1][3])));
      if (!__all(mloc - m[f] <= 8.f)) {
        mloc = fmaxf(mloc, __shfl_xor(mloc, 16));
        mloc = fmaxf(mloc, __shfl_xor(mloc, 32));
        const float mn = fmaxf(m[f], mloc);
        const float r = exp2f((m[f] - mn)*kL2E);
        m[f] = mn;
        l[f] *= r;
        const float rr0 = __shfl(r, hi*4+0), rr1 = __shfl(r, hi*4+1);
        const float rr2 = __shfl(r, hi*4+2), rr3 = __shfl(r, hi*4+3);
        #pragma unroll
        for (int db = 0; db < 4; ++db) {
          acc[f][db][0] *= rr0; acc[f][db][1] *= rr1;
          acc[f][db][2] *= rr2; acc[f][db][3] *= rr3;
        }
      }
      float p[8], ls = 0.f;
      #pragma unroll
      for (int t = 0; t < 2; ++t)
        #pragma unroll
        for (int j = 0; j < 4; ++j) {
          const float pv = exp2f((st[t][j] - m[f])*kL2E);
          p[t*4+j] = pv; ls += pv;
        }
      l[f] += ls;
      const unsigned c00 = pk2(p[0], p[1]);
      const unsigned c01 = pk2(p[2], p[3]);
      const unsigned c10 = pk2(p[4], p[5]);
      const unsigned c11 = pk2(p[6], p[7]);
      const unsigned c00x = __shfl_xor((int)c00, 32), c10x = __shfl_xor((int)c10, 32);
      const unsigned c01x = __shfl_xor((int)c01, 32), c11x = __shfl_xor((int)c11, 32);
      const unsigned E = up ? c10x : c00, F = up ? c10 : c00x;
      const unsigned G = up ? c11x : c01, H = up ? c11 : c01x;
      const unsigned Ex = __shfl_xor((int)E, 16), Fx = __shfl_xor((int)F, 16);
      const unsigned Gx = __shfl_xor((int)G, 16), Hx = __shfl_xor((int)H, 16);
      union { unsigned w[4]; s16x8 v; } pw;
      pw.w[0] = subhi ? Fx : E;
      pw.w[1] = subhi ? Hx : G;
      pw.w[2] = subhi ? F  : Ex;
      pw.w[3] = subhi ? H  : Gx;
      pa[f] = pw.v;
    }
    #pragma unroll
    for (int db = 0; db < 4; ++db) {
      const s16x8 vf = *(const s16x8*)(Vg + ((size_t)(db*16 + qr))*kM + k0 + hi*8);
      #pragma unroll
      for (int f = 0; f < 4; ++f)
        acc[f][db] = __builtin_amdgcn_mfma_f32_16x16x32_bf16(pa[f], vf, acc[f][db], 0, 0, 0);
    }
  }

  const int b = bh >> 2, h = bh & 3;
  u16* outp = ctx5 + (size_t)split*kTOK;
  #pragma unroll
  for (int f = 0; f < 4; ++f) {
    float lf = l[f];
    lf += __shfl_xor(lf, 16); lf += __shfl_xor(lf, 32);
    const float li = 0.2f/lf;
    const float l0 = __shfl(li, hi*4+0), l1 = __shfl(li, hi*4+1);
    const float l2 = __shfl(li, hi*4+2), l3 = __shfl(li, hi*4+3);
    #pragma unroll
    for (int db = 0; db < 4; ++db) {
      const size_t base = ((size_t)((b*kN + col)*kM + q0 + f*16 + hi*4))*kD + h*kHD + db*16 + qr;
      outp[base + 0*kD] = f2b(acc[f][db][0]*l0);
      outp[base + 1*kD] = f2b(acc[f][db][1]*l1);
      outp[base + 2*kD] = f2b(acc[f][db][2]*l2);
      outp[base + 3*kD] = f2b(acc[f][db][3]*l3);
    }
  }
}

__global__ __launch_bounds__(256) void sum5_k(const u16* __restrict__ c5,
                                              u16* __restrict__ outU)
{
  const size_t i4 = ((size_t)blockIdx.x*256 + threadIdx.x)*4;
  float s0=0.f, s1=0.f, s2=0.f, s3=0.f;
  #pragma unroll
  for (int sp = 0; sp < 5; ++sp) {
    uint2 d = *(const uint2*)(c5 + sp*kTOK + i4);
    s0 += b2f((u16)(d.x & 0xffff)); s1 += b2f((u16)(d.x >> 16));
    s2 += b2f((u16)(d.y & 0xffff)); s3 += b2f((u16)(d.y >> 16));
  }
  union { u16 u[4]; uint2 d; } o;
  o.u[0]=f2b(s0); o.u[1]=f2b(s1); o.u[2]=f2b(s2); o.u[3]=f2b(s3);
  *(uint2*)(outU + i4) = o.d;
}

// LayerNorm(512) + exact GELU: wave per row, bf16 in/out, no LDS.
__global__ __launch_bounds__(256) void lngelu_k(
    const u16* __restrict__ x, u16* __restrict__ y,
    const float* __restrict__ g0, const float* __restrict__ b0,
    const float* __restrict__ g1, const float* __restrict__ b1, int Mh)
{
  const int w = threadIdx.x >> 6, lane = threadIdx.x & 63;
  const int row = blockIdx.x*4 + w;
  const float* g = (row < Mh) ? g0 : g1;
  const float* bb = (row < Mh) ? b0 : b1;
  const int o8 = lane*8;
  union { u16 u[8]; s16x8 v; } xv;
  xv.v = *(const s16x8*)(x + (size_t)row*512 + o8);
  float vf[8];
  float s1 = 0.f, s2 = 0.f;
  #pragma unroll
  for (int j = 0; j < 8; ++j) {
    vf[j] = b2f(xv.u[j]);
    s1 += vf[j]; s2 += vf[j]*vf[j];
  }
  s1 = wred_sum(s1); s2 = wred_sum(s2);
  const float mean = s1 * (1.f/512.f);
  const float ms   = s2 * (1.f/512.f);
  const float rs = rsqrtf(ms - mean*mean + 1e-5f);
  f32x4 gv0 = *(const f32x4*)(g + o8),  gv1 = *(const f32x4*)(g + o8 + 4);
  f32x4 bv0 = *(const f32x4*)(bb + o8), bv1 = *(const f32x4*)(bb + o8 + 4);
  union { u16 u[8]; s16x8 v; } ov;
  #pragma unroll
  for (int j = 0; j < 8; ++j) {
    const float gj = (j < 4) ? gv0[j] : gv1[j-4];
    const float bj = (j < 4) ? bv0[j] : bv1[j-4];
    const float yv = (vf[j]-mean)*rs*gj + bj;
    ov.u[j] = f2b(0.5f*yv*(1.f+erff(yv*0.70710678118654752f)));
  }
  *(s16x8*)(y + (size_t)row*512 + o8) = ov.v;
}

__global__ void conf_dot_k(const float* __restrict__ tmp, const float* __restrict__ w2,
                           const float* __restrict__ b2, float* __restrict__ out)
{
  const int w = threadIdx.x >> 6, lane = threadIdx.x & 63;
  const int row = blockIdx.x*4 + w;
  const float* t = tmp + (size_t)row*kD;
  float s = 0.f;
  #pragma unroll
  for (int j=0;j<4;++j) s = fmaf(t[lane+j*64], w2[lane+j*64], s);
  s = wred_sum(s);
  if (lane == 0) out[row] = s + b2[0];
}

// ---------------------------------------------------------------------------
extern "C" void kernel_launch(void* const* d_in, const int* in_sizes, int n_in,
                              void* d_out, int out_size, void* d_ws, size_t ws_size,
                              hipStream_t stream)
{
  auto F = [&](int i){ return (const float*)d_in[i]; };
  const float* t_desc = F(0);
  const float* s_desc = F(1);
  const float* t_enc  = F(2);
  const float* s_enc  = F(3);
  const float* q_enc  = F(4);
  const float* k_enc  = F(5);

  // ---- workspace map ----
  char* base = (char*)d_ws;
  float* xts = (float*)base;                     // 12288x256 f32 (xt|xs)
  float* xt = xts;
  float* xs = xts + kTOK;
  char* R1  = base + 2*kTOK*sizeof(float);       // 25.17 MB multi-use
  char* CTX = R1 + 4*kTOK*sizeof(float);         // 6.29 MB
  char* MSG = CTX + 2*kTOK*sizeof(u16);          // 6.29 MB
  u16* Qb16 = (u16*)(MSG + kTOK*sizeof(float));
  u16* Kb16 = Qb16 + 2*kTOK;
  u16* Vt16 = Kb16 + 2*kTOK;
  u16* wsW  = Vt16 + 2*kTOK;
  // aliases
  u16*   qkvU  = (u16*)R1;                       // 12288x768 bf16
  u16*   yH    = (u16*)R1;                       // 12288x512 bf16 (f1 out)
  u16*   ctx5  = qkvU + (size_t)kRowsH*768;      // 5 x 6144x256 bf16 (after t-half qkv)
  float* Wtmp  = (float*)R1;                     // 4 x 256x512 f32 (prep-time only)
  u16*   ctxU  = (u16*)CTX;                      // 12288x256
  float* Qs2s  = (float*)MSG;                    // 48x512x64 f32
  float* confb = (float*)MSG;                    // 6144x256 f32
  u16*   yU    = (u16*)CTX;                      // 12288x512 (spans CTX+MSG)

  float* out_t2s2 = (float*)d_out;
  float* out_conf = (float*)d_out + 2*kTOK;

  // ---- weight cast table (tiled Bs-image layout, W' fusion) ----
  WtTable tab;
  int nd = 0, total_tiles = 0;
  size_t woff = 0;
  const u16* wp[18];
  auto addw = [&](int idx, const float* W2, int K, int N){
    u16* dst = wsW + woff;
    tab.d[nd] = { F(idx), W2, dst, K, N, (N>>7)*(K>>5) };
    total_tiles += tab.d[nd].ntiles;
    wp[nd] = dst;
    woff += (size_t)K*N;
    ++nd;
    return nd-1;
  };
  const int W_SA_QKV = addw(6,  nullptr, 256, 768);
  const int W_SA_F1  = addw(10, Wtmp + 0*131072, 512, 512);
  const int W_SA_F2  = addw(14, nullptr, 512, 256);
  const int W_SS_QKV = addw(16, nullptr, 256, 768);
  const int W_SS_F1  = addw(20, Wtmp + 1*131072, 512, 512);
  const int W_SS_F2  = addw(24, nullptr, 512, 256);
  const int W_TT_QKV = addw(26, nullptr, 256, 768);
  const int W_TT_F1  = addw(30, Wtmp + 2*131072, 512, 512);
  const int W_TT_F2  = addw(34, nullptr, 512, 256);
  const int W_CA_Q   = addw(36, nullptr, 256, 256);  // contiguous with W_CA_KV
  const int W_CA_KV  = addw(38, nullptr, 256, 512);
  const int W_CA_F1  = addw(42, Wtmp + 3*131072, 512, 512);
  const int W_CA_F2  = addw(46, nullptr, 512, 256);
  const int W_CF_1   = addw(48, nullptr, 256, 256);
  (void)W_CA_KV;
  float* b1p = (float*)(wsW + woff);             // 4 x 512 f32 fused biases

  FuseArgs fa;
  fa.Wout[0]=F(8);  fa.Wout[1]=F(18); fa.Wout[2]=F(28); fa.Wout[3]=F(40);
  fa.W1[0]=F(10);   fa.W1[1]=F(20);   fa.W1[2]=F(30);   fa.W1[3]=F(42);
  fa.bout[0]=F(9);  fa.bout[1]=F(19); fa.bout[2]=F(29); fa.bout[3]=F(41);
  fa.b1[0]=F(11);   fa.b1[1]=F(21);   fa.b1[2]=F(31);   fa.b1[3]=F(43);
  fa.Wtmp = Wtmp; fa.b1p = b1p;
  wfuse_k<<<136, 256, 0, stream>>>(fa);
  wtcast_k<<<total_tiles, 256, 0, stream>>>(tab);

  // mmad launchers (dual row-segment, 12288 rows)
  auto mm_f32_to_b16 = [&](const float* a1a, const float* a1b, int wa, int wb2,
                           const float* ba, const float* bb2, u16* c, int N_, int K_){
    dim3 grid(N_/128, kRows/128);
    mmad_k<false,false,true><<<grid,256,0,stream>>>(a1a, a1b, nullptr, nullptr, K_,
        wp[wa], wp[wb2], ba, bb2, ba, bb2, N_, nullptr, nullptr, c, N_, K_, kRowsH, 0);
  };
  // fused f1: A = concat(x f32, ctx bf16), W = [W1_top; W'], bias = b1' -> bf16
  auto mm_f1 = [&](const float* a1a, const float* a1b, const u16* a2a, const u16* a2b,
                   int wa, int wb2, const float* ba, const float* bb2, u16* c){
    dim3 grid(512/128, kRows/128);
    mmad_k<false,true,true><<<grid,256,0,stream>>>(a1a, a1b, a2a, a2b, 256,
        wp[wa], wp[wb2], ba, bb2, ba, bb2, 512, nullptr, nullptr, c, 512, 512, kRowsH, 0);
  };
  auto mm_f2 = [&](const u16* a1a, const u16* a1b, int wa, int wb2,
                   const float* ba, const float* bb2,
                   const float* ra, const float* rb, float* c){
    dim3 grid(256/128, kRows/128);
    mmad_k<true,false,false><<<grid,256,0,stream>>>(a1a, a1b, nullptr, nullptr, 512,
        wp[wa], wp[wb2], ba, bb2, ba, bb2, 256, ra, rb, c, 256, 512, kRowsH, 0);
  };

  // ================= SELF (t || s, shared sa weights) =================
  mm_f32_to_b16(t_desc, s_desc, W_SA_QKV, W_SA_QKV, F(7), F(7), qkvU, 768, 256);
  prep_self_k<<<kGrp*8, 256, 0, stream>>>(qkvU, t_enc, s_enc, Qb16, Kb16, Vt16);
  attn_mm_k<0><<<192, 256, 0, stream>>>(Qb16, Kb16, Vt16, ctxU);
  mm_f1(t_desc, s_desc, ctxU, ctxU + kTOK, W_SA_F1, W_SA_F1, b1p+0*512, b1p+0*512, yH);
  lngelu_k<<<kRows/4, 256, 0, stream>>>(yH, yU, F(12), F(13), F(12), F(13), kRowsH);
  mm_f2(yU, yU + (size_t)kRowsH*512, W_SA_F2, W_SA_F2, F(15), F(15), t_desc, s_desc, xts);

  // ================= TT (t) || SS (s) =================
  mm_f32_to_b16(xt, xs, W_TT_QKV, W_SS_QKV, F(27), F(17), qkvU, 768, 256);
  prep_s2s_k<<<kGrpH*8, 256, 0, stream>>>(qkvU, k_enc, Qs2s, Kb16, Vt16);
  attn_comb_k<<<480 + 6144, 256, 0, stream>>>(Qs2s, Kb16, Vt16, q_enc, ctx5, qkvU, ctxU);
  sum5_k<<<(int)(kTOK/1024), 256, 0, stream>>>(ctx5, ctxU + kTOK);
  mm_f1(xt, xs, ctxU, ctxU + kTOK, W_TT_F1, W_SS_F1, b1p+2*512, b1p+1*512, yH);
  lngelu_k<<<kRows/4, 256, 0, stream>>>(yH, yU, F(32), F(33), F(22), F(23), kRowsH);
  mm_f2(yU, yU + (size_t)kRowsH*512, W_TT_F2, W_SS_F2, F(35), F(25), xt, xs, xts);

  // ================= CONF (from xs post-s2s) =================
  {
    dim3 grid(2, kRowsH/128);
    mmad_k<false,false,false><<<grid,256,0,stream>>>(xs, xs, nullptr, nullptr, 256,
        wp[W_CF_1], wp[W_CF_1], F(49), F(49), F(49), F(49), 256,
        nullptr, nullptr, confb, 256, 256, kRowsH, 1);
  }
  conf_dot_k<<<kRowsH/4, 256, 0, stream>>>(confb, F(50), F(51), out_conf);

  // ================= CROSS (merged q+kv GEMM) =================
  {
    dim3 grid(768/128, kRows/128);
    mmad_k<false,false,true><<<grid,256,0,stream>>>(xt, xs, nullptr, nullptr, 256,
        wp[W_CA_Q], wp[W_CA_Q], F(37), F(37), F(39), F(39), 256,
        nullptr, nullptr, qkvU, 768, 256, kRowsH, 0);
  }
  prep_cross_k<<<kGrp*8, 256, 0, stream>>>(qkvU, Kb16, Vt16);
  attn_mm_k<1><<<192, 256, 0, stream>>>(qkvU, Kb16, Vt16, ctxU);
  mm_f1(xt, xs, ctxU, ctxU + kTOK, W_CA_F1, W_CA_F1, b1p+3*512, b1p+3*512, yH);
  lngelu_k<<<kRows/4, 256, 0, stream>>>(yH, yU, F(44), F(45), F(44), F(45), kRowsH);
  mm_f2(yU, yU + (size_t)kRowsH*512, W_CA_F2, W_CA_F2, F(47), F(47), xt, xs, out_t2s2);
}

// Round 18
// 442.020 us; speedup vs baseline: 1.0132x; 1.0132x over previous
//
#include <hip/hip_runtime.h>
#include <hip/hip_bf16.h>
#include <math.h>

// Problem constants
constexpr int kD   = 256;
constexpr int kH   = 4;
constexpr int kHD  = 64;
constexpr int kB   = 2;
constexpr int kN   = 6;
constexpr int kM   = 512;
constexpr int kRowsH = kB*kN*kM;          // 6144
constexpr int kRows  = 2*kRowsH;          // 12288
constexpr int kGrpH  = kB*kN*kH;          // 48
constexpr int kGrp   = 2*kGrpH;           // 96
constexpr size_t kTOK = (size_t)kRowsH*kD;        // 1,572,864
constexpr size_t kEncSlab = (size_t)kN*kM*kHD;    // 196608
constexpr size_t kQEncSlab = (size_t)kN*kN*kHD;   // 2304
constexpr float kL2E = 1.4426950408889634f;

typedef unsigned short u16;
typedef __attribute__((ext_vector_type(8))) short s16x8;
typedef __attribute__((ext_vector_type(4))) float f32x4;

__device__ __forceinline__ float wred_sum(float v){
  #pragma unroll
  for (int m=32;m>0;m>>=1) v += __shfl_xor(v, m, 64);
  return v;
}
__device__ __forceinline__ u16 f2b(float x){
  union { float f; unsigned u; } a; a.f = x;
  unsigned r = a.u + 0x7fffu + ((a.u >> 16) & 1u);
  return (u16)(r >> 16);
}
__device__ __forceinline__ float b2f(u16 x){
  union { unsigned u; float f; } a; a.u = ((unsigned)x) << 16;
  return a.f;
}
__device__ __forceinline__ unsigned pk2(float lo, float hi){
  union { __hip_bfloat162 h2; unsigned u; } c;
  c.h2 = __float22bfloat162_rn(make_float2(lo, hi));
  return c.u;
}

// ---------------------------------------------------------------------------
// FFN out-proj fusion precompute: W' = Wout @ W1_bot, b1' = b1 + bout @ W1_bot
// Blocks [0,128): W' tiles. Blocks [128,136): fused biases.
// ---------------------------------------------------------------------------
struct FuseArgs {
  const float* Wout[4]; const float* W1[4];
  const float* bout[4]; const float* b1[4];
  float* Wtmp; float* b1p;
};

__global__ __launch_bounds__(256) void wfuse_k(FuseArgs fa)
{
  if (blockIdx.x >= 128) {
    const int bb = blockIdx.x - 128;
    const int set = bb >> 1;
    const int n = (bb & 1)*256 + threadIdx.x;
    const float* W1 = fa.W1[set];
    const float* bo = fa.bout[set];
    float s = fa.b1[set][n];
    for (int k = 0; k < 256; ++k)
      s = fmaf(bo[k], W1[(size_t)(256+k)*512 + n], s);
    fa.b1p[set*512 + n] = s;
    return;
  }
  const int set = blockIdx.x >> 5;
  const int t = blockIdx.x & 31;
  const int row0 = (t >> 3)*64, col0 = (t & 7)*64;
  const float* A  = fa.Wout[set];            // 256x256
  const float* Bm = fa.W1[set] + 256*512;    // rows 256..511, ld 512
  float* C = fa.Wtmp + (size_t)set*(256*512);
  __shared__ float As[16][65];
  __shared__ float Bs[16][64];
  const int tid = threadIdx.x;
  const int tx = tid & 15, ty = tid >> 4;
  const int ar = tid >> 2, ak = (tid & 3)*4;
  const int wr = tid >> 4, wc = (tid & 15)*4;
  float acc[4][4] = {};
  for (int kt = 0; kt < 256; kt += 16) {
    float4 av = *(const float4*)(A + (size_t)(row0+ar)*256 + kt + ak);
    As[ak+0][ar]=av.x; As[ak+1][ar]=av.y; As[ak+2][ar]=av.z; As[ak+3][ar]=av.w;
    *(float4*)(&Bs[wr][wc]) = *(const float4*)(Bm + (size_t)(kt+wr)*512 + col0 + wc);
    __syncthreads();
    #pragma unroll
    for (int k2=0;k2<16;++k2) {
      float a[4], b[4];
      #pragma unroll
      for (int i=0;i<4;++i) a[i]=As[k2][ty*4+i];
      #pragma unroll
      for (int j=0;j<4;++j) b[j]=Bs[k2][tx*4+j];
      #pragma unroll
      for (int i=0;i<4;++i)
        #pragma unroll
        for (int j=0;j<4;++j) acc[i][j] = fmaf(a[i], b[j], acc[i][j]);
    }
    __syncthreads();
  }
  #pragma unroll
  for (int i=0;i<4;++i)
    #pragma unroll
    for (int j=0;j<4;++j)
      C[(size_t)(row0+ty*4+i)*512 + col0+tx*4+j] = acc[i][j];
}

// ---------------------------------------------------------------------------
// Weight cast into GEMM staging-tile image (Bs LDS image, swizzle baked in).
// ---------------------------------------------------------------------------
struct WtDesc { const float* W; const float* W2; u16* Wt; int K; int N; int ntiles; };
struct WtTable { WtDesc d[18]; };

__global__ __launch_bounds__(256) void wtcast_k(WtTable tab)
{
  int t = blockIdx.x, mi = 0;
  while (t >= tab.d[mi].ntiles) { t -= tab.d[mi].ntiles; ++mi; }
  const float* W = tab.d[mi].W;
  const float* W2 = tab.d[mi].W2;
  u16* Wt = tab.d[mi].Wt;
  const int K = tab.d[mi].K, N = tab.d[mi].N;
  const int ktn = K >> 5;
  const int nt = t / ktn, kt = t % ktn;
  const int n0 = nt*128, k0 = kt*32;
  u16* dst = Wt + (size_t)t*4096;
  #pragma unroll
  for (int s = 0; s < 2; ++s) {
    const int idx0 = (s*256 + (int)threadIdx.x)*8;
    const int ar = idx0 >> 5;
    const int w8 = (idx0 >> 3) & 3;
    const int sw = (ar >> 1) & 3;
    int kk = k0 + ((w8 ^ sw) << 3);
    const int n  = n0 + ar;
    const float* src = W;
    if (W2 && kk >= 256) { src = W2; kk -= 256; }
    union { u16 u[8]; s16x8 v; } o;
    #pragma unroll
    for (int e = 0; e < 8; ++e)
      o.u[e] = f2b(src[(size_t)(kk + e)*N + n]);
    *(s16x8*)(dst + idx0) = o.v;
  }
}

// ---------------------------------------------------------------------------
// bf16 MFMA GEMM, dual row-segment + dual col-segment bias. 2-phase
// double-buffered LDS. XCD-bijective block swizzle.
// ---------------------------------------------------------------------------
template<bool A1B, bool A2B, bool CB>
__global__ __launch_bounds__(256) void mmad_k(
    const void* __restrict__ A1a, const void* __restrict__ A1b,
    const void* __restrict__ A2a, const void* __restrict__ A2b, int K1,
    const u16* __restrict__ Wa, const u16* __restrict__ Wb,
    const float* __restrict__ bia, const float* __restrict__ bib,
    const float* __restrict__ bi2a, const float* __restrict__ bi2b, int Ns,
    const float* __restrict__ Ra, const float* __restrict__ Rb,
    void* __restrict__ Cp, int N, int K, int Mh, int doRelu)
{
  __shared__ u16 As[2][128*32];
  __shared__ u16 Bs[2][128*32];
  const int tid = threadIdx.x;
  const int lane = tid & 63, w = tid >> 6;
  const int gx = gridDim.x;
  const int nblk = gx * gridDim.y;
  int flat = blockIdx.y*gx + blockIdx.x;
  if (!(nblk & 7)) flat = (flat & 7)*(nblk >> 3) + (flat >> 3);
  const int bxx = flat % gx, byy = flat / gx;
  const int row0 = byy*128, col0 = bxx*128;
  const bool sec = (row0 >= Mh);
  const int lr0 = sec ? row0 - Mh : row0;
  const void* A1 = sec ? A1b : A1a;
  const void* A2 = sec ? A2b : A2a;
  const u16* Wt  = sec ? Wb : Wa;
  const float* bias  = sec ? bib : bia;
  const float* bias2 = sec ? bi2b : bi2a;
  const float* R = sec ? Rb : Ra;
  const int wr = (w >> 1)*64, wc = (w & 1)*64;
  const int ar = tid >> 1, ah = tid & 1;
  const int K2 = K - K1;
  const int ktn = K >> 5;
  f32x4 acc[4][4] = {};

  auto stage = [&](int buf, int kt) {
    const u16* wtile = Wt + ((size_t)((col0 >> 7)*ktn + (kt >> 5)))*4096;
    #pragma unroll
    for (int s = 0; s < 2; ++s) {
      const u16* srcp = wtile + (size_t)(s*256 + tid)*8;
      __builtin_amdgcn_global_load_lds(
          (const __attribute__((address_space(1))) void*)srcp,
          (__attribute__((address_space(3))) void*)((char*)Bs[buf] + s*4096 + w*1024),
          16, 0, 0);
    }
    const int kk = kt + ah*16;
    union { u16 u[16]; s16x8 v[2]; } tmp;
    if (kk < K1) {
      if constexpr (A1B) {
        const u16* ap = (const u16*)A1 + (size_t)(lr0+ar)*K1 + kk;
        tmp.v[0] = *(const s16x8*)ap; tmp.v[1] = *(const s16x8*)(ap+8);
      } else {
        const float* ap = (const float*)A1 + (size_t)(lr0+ar)*K1 + kk;
        #pragma unroll
        for (int i = 0; i < 16; i += 4) {
          f32x4 v4 = *(const f32x4*)(ap + i);
          tmp.u[i+0]=f2b(v4.x); tmp.u[i+1]=f2b(v4.y); tmp.u[i+2]=f2b(v4.z); tmp.u[i+3]=f2b(v4.w);
        }
      }
    } else {
      if constexpr (A2B) {
        const u16* ap = (const u16*)A2 + (size_t)(lr0+ar)*K2 + (kk - K1);
        tmp.v[0] = *(const s16x8*)ap; tmp.v[1] = *(const s16x8*)(ap+8);
      } else {
        const float* ap = (const float*)A2 + (size_t)(lr0+ar)*K2 + (kk - K1);
        #pragma unroll
        for (int i = 0; i < 16; i += 4) {
          f32x4 v4 = *(const f32x4*)(ap + i);
          tmp.u[i+0]=f2b(v4.x); tmp.u[i+1]=f2b(v4.y); tmp.u[i+2]=f2b(v4.z); tmp.u[i+3]=f2b(v4.w);
        }
      }
    }
    const int sw = (ar >> 1) & 3;
    *(s16x8*)(&As[buf][ar*32 + ((ah*2+0)^sw)*8]) = tmp.v[0];
    *(s16x8*)(&As[buf][ar*32 + ((ah*2+1)^sw)*8]) = tmp.v[1];
  };

  stage(0, 0);
  __syncthreads();
  for (int t = 0; t < ktn; ++t) {
    const int cur = t & 1;
    if (t + 1 < ktn) stage(cur ^ 1, (t + 1) << 5);
    s16x8 af[4], bfv[4];
    #pragma unroll
    for (int fm = 0; fm < 4; ++fm) {
      const int r = wr + fm*16 + (lane & 15);
      const int g = (lane >> 4) ^ ((r >> 1) & 3);
      af[fm] = *(const s16x8*)(&As[cur][r*32 + g*8]);
    }
    #pragma unroll
    for (int fn = 0; fn < 4; ++fn) {
      const int c = wc + fn*16 + (lane & 15);
      const int g = (lane >> 4) ^ ((c >> 1) & 3);
      bfv[fn] = *(const s16x8*)(&Bs[cur][c*32 + g*8]);
    }
    #pragma unroll
    for (int fm = 0; fm < 4; ++fm)
      #pragma unroll
      for (int fn = 0; fn < 4; ++fn)
        acc[fm][fn] = __builtin_amdgcn_mfma_f32_16x16x32_bf16(af[fm], bfv[fn], acc[fm][fn], 0, 0, 0);
    __syncthreads();
  }

  #pragma unroll
  for (int fm = 0; fm < 4; ++fm) {
    const int ro = wr + fm*16 + (lane >> 4)*4;
    #pragma unroll
    for (int fn = 0; fn < 4; ++fn) {
      const int cc = col0 + wc + fn*16 + (lane & 15);
      const float bv = (cc < Ns) ? bias[cc] : bias2[cc - Ns];
      #pragma unroll
      for (int j = 0; j < 4; ++j) {
        float v = acc[fm][fn][j] + bv;
        if (R) v += R[(size_t)(lr0 + ro + j)*N + cc];
        if (doRelu) v = fmaxf(v, 0.f);
        const size_t idx = (size_t)(row0 + ro + j)*N + cc;
        if constexpr (CB) ((u16*)Cp)[idx] = f2b(v);
        else              ((float*)Cp)[idx] = v;
      }
    }
  }
}

// ---------------------------------------------------------------------------
// Preps (read bf16 qkv/kv): emit bf16 K [g][key][64], bf16 Vt [g][64][key],
// and Q (self: roped+0.125-prescaled bf16; s2s: raw f32; cross: K prescaled).
// ---------------------------------------------------------------------------
__global__ __launch_bounds__(256) void prep_self_k(
    const u16* __restrict__ qkvU, const float* __restrict__ t_enc,
    const float* __restrict__ s_enc,
    u16* __restrict__ Qb, u16* __restrict__ Kb, u16* __restrict__ Vt)
{
  __shared__ u16 vs[64][66];
  const int g = blockIdx.x >> 3, i0 = (blockIdx.x & 7)*64;
  const int h = g & 3, bn = g >> 2;
  const float* enc = (bn < 12) ? t_enc : s_enc;
  const int n = (bn < 12 ? bn : bn - 12) % kN;
  const int c = threadIdx.x & 63, t4 = threadIdx.x >> 6;
  const float sgn = (c & 1) ? 1.f : -1.f;
  #pragma unroll 4
  for (int rr = 0; rr < 16; ++rr) {
    const int il = rr*4 + t4, i = i0 + il;
    const u16* base = qkvU + ((size_t)bn*kM + i)*768 + h*192;
    const float q = b2f(base[c*3]), k = b2f(base[c*3+1]);
    const float qp = b2f(base[(c^1)*3]), kp = b2f(base[(c^1)*3+1]);
    const size_t eo = ((size_t)(n*kM + i))*kHD + c;
    const float e0 = enc[eo], e1 = enc[kEncSlab + eo];
    Qb[((size_t)g*kM + i)*kHD + c] = f2b((q*e0 + sgn*qp*e1)*0.125f);
    Kb[((size_t)g*kM + i)*kHD + c] = f2b(k*e0 + sgn*kp*e1);
    vs[il][c] = base[c*3+2];
  }
  __syncthreads();
  #pragma unroll 4
  for (int rr = 0; rr < 16; ++rr) {
    const int cc = rr*4 + t4;
    Vt[((size_t)g*kHD + cc)*kM + i0 + c] = vs[c][cc];
  }
}

__global__ __launch_bounds__(256) void prep_s2s_k(
    const u16* __restrict__ qkvU, const float* __restrict__ kenc,
    float* __restrict__ Qs, u16* __restrict__ Kb, u16* __restrict__ Vt)
{
  __shared__ u16 vs[64][66];
  const int g = blockIdx.x >> 3, i0 = (blockIdx.x & 7)*64;   // g = bh*6+view
  const int view = g % kN, bh = g / kN;
  const int h = bh & 3, b = bh >> 2;
  const int c = threadIdx.x & 63, t4 = threadIdx.x >> 6;
  const float sgn = (c & 1) ? 1.f : -1.f;
  #pragma unroll 4
  for (int rr = 0; rr < 16; ++rr) {
    const int il = rr*4 + t4, i = i0 + il;
    const u16* base = qkvU + ((size_t)(kRowsH + (b*kN+view)*kM + i))*768 + h*192;
    const float k = b2f(base[c*3+1]), kp = b2f(base[(c^1)*3+1]);
    const size_t eo = ((size_t)(view*kM + i))*kHD + c;
    const float e0 = kenc[eo], e1 = kenc[kEncSlab + eo];
    Qs[((size_t)g*kM + i)*kHD + c] = b2f(base[c*3]);
    Kb[((size_t)g*kM + i)*kHD + c] = f2b(k*e0 + sgn*kp*e1);
    vs[il][c] = base[c*3+2];
  }
  __syncthreads();
  #pragma unroll 4
  for (int rr = 0; rr < 16; ++rr) {
    const int cc = rr*4 + t4;
    Vt[((size_t)g*kHD + cc)*kM + i0 + c] = vs[c][cc];
  }
}

__global__ __launch_bounds__(256) void prep_cross_k(
    const u16* __restrict__ qkvC, u16* __restrict__ Kb, u16* __restrict__ Vt)
{
  __shared__ u16 vs[64][66];
  const int g = blockIdx.x >> 3, i0 = (blockIdx.x & 7)*64;
  const int h = g & 3, bn = g >> 2;
  const int src = (bn < 12) ? bn + 12 : bn - 12;
  const int c = threadIdx.x & 63, t4 = threadIdx.x >> 6;
  #pragma unroll 4
  for (int rr = 0; rr < 16; ++rr) {
    const int il = rr*4 + t4, i = i0 + il;
    const u16* base = qkvC + ((size_t)src*kM + i)*768 + 256 + h*128;
    Kb[((size_t)g*kM + i)*kHD + c] = f2b(b2f(base[c*2]) * 0.125f);
    vs[il][c] = base[c*2+1];
  }
  __syncthreads();
  #pragma unroll 4
  for (int rr = 0; rr < 16; ++rr) {
    const int cc = rr*4 + t4;
    Vt[((size_t)g*kHD + cc)*kM + i0 + c] = vs[c][cc];
  }
}

// ---------------------------------------------------------------------------
// self/cross attention, software-pipelined: 32 q-rows/wave (2 fragments).
// Defer-max online softmax with shfl-free guard. 384 blocks, XCD-bijective.
// ---------------------------------------------------------------------------
template<int CROSSQ>
__global__ __launch_bounds__(256) void attn_mm_k(
    const u16* __restrict__ Qb, const u16* __restrict__ Kb,
    const u16* __restrict__ Vt, u16* __restrict__ ctx)
{
  const int w = threadIdx.x >> 6, lane = threadIdx.x & 63;
  const int bij = (blockIdx.x & 7)*48 + (blockIdx.x >> 3);   // 384
  const int g = bij >> 2, qblk = bij & 3;
  const int h = g & 3, bn = g >> 2;
  const int q0 = qblk*128 + w*32;
  const int qr = lane & 15, hi = lane >> 4;
  const bool subhi = (hi & 1), up = (hi >= 2);

  s16x8 qf0[2], qf1[2];
  #pragma unroll
  for (int f = 0; f < 2; ++f) {
    const u16* qp = CROSSQ
      ? Qb + ((size_t)(bn*kM + q0 + f*16 + qr))*768 + h*kHD + hi*8
      : Qb + ((size_t)g*kM + q0 + f*16 + qr)*kHD + hi*8;
    qf0[f] = *(const s16x8*)(qp);
    qf1[f] = *(const s16x8*)(qp + 32);
  }

  const u16* Kg = Kb + (size_t)g*kM*kHD;
  const u16* Vg = Vt + (size_t)g*kHD*kM;
  f32x4 acc[2][4] = {};
  float m[2] = {-1e30f, -1e30f}, l[2] = {0.f, 0.f};

  s16x8 kA[2][2], kB[2][2];
  f32x4 sA[2][2], sB[2][2];

  auto loadK = [&](s16x8 kb[2][2], int kc){
    #pragma unroll
    for (int t = 0; t < 2; ++t) {
      const u16* kp = Kg + ((size_t)(kc*32 + t*16 + qr))*kHD + hi*8;
      kb[t][0] = *(const s16x8*)(kp);
      kb[t][1] = *(const s16x8*)(kp + 32);
    }
  };
  auto qk = [&](const s16x8 kb[2][2], f32x4 st[2][2]){
    #pragma unroll
    for (int f = 0; f < 2; ++f)
      #pragma unroll
      for (int t = 0; t < 2; ++t) {
        f32x4 z = {0.f, 0.f, 0.f, 0.f};
        z = __builtin_amdgcn_mfma_f32_16x16x32_bf16(kb[t][0], qf0[f], z, 0, 0, 0);
        z = __builtin_amdgcn_mfma_f32_16x16x32_bf16(kb[t][1], qf1[f], z, 0, 0, 0);
        st[f][t] = z;
      }
  };
  auto smpv = [&](f32x4 st[2][2], int kc){
    const int k0 = kc*32;
    s16x8 pa[2];
    #pragma unroll
    for (int f = 0; f < 2; ++f) {
      float mloc = fmaxf(fmaxf(fmaxf(st[f][0][0], st[f][0][1]), fmaxf(st[f][0][2], st[f][0][3])),
                         fmaxf(fmaxf(st[f][1][0], st[f][1][1]), fmaxf(st[f][1][2], st[f][1][3])));
      if (!__all(mloc - m[f] <= 8.f)) {
        mloc = fmaxf(mloc, __shfl_xor(mloc, 16));
        mloc = fmaxf(mloc, __shfl_xor(mloc, 32));
        const float mn = fmaxf(m[f], mloc);
        const float r = exp2f((m[f] - mn)*kL2E);
        m[f] = mn;
        l[f] *= r;
        const float rr0 = __shfl(r, hi*4+0), rr1 = __shfl(r, hi*4+1);
        const float rr2 = __shfl(r, hi*4+2), rr3 = __shfl(r, hi*4+3);
        #pragma unroll
        for (int db = 0; db < 4; ++db) {
          acc[f][db][0] *= rr0; acc[f][db][1] *= rr1;
          acc[f][db][2] *= rr2; acc[f][db][3] *= rr3;
        }
      }
      float p[8], ls = 0.f;
      #pragma unroll
      for (int t = 0; t < 2; ++t)
        #pragma unroll
        for (int j = 0; j < 4; ++j) {
          const float pv = exp2f((st[f][t][j] - m[f])*kL2E);
          p[t*4+j] = pv; ls += pv;
        }
      l[f] += ls;
      const unsigned c00 = pk2(p[0], p[1]);
      const unsigned c01 = pk2(p[2], p[3]);
      const unsigned c10 = pk2(p[4], p[5]);
      const unsigned c11 = pk2(p[6], p[7]);
      const unsigned c00x = __shfl_xor((int)c00, 32), c10x = __shfl_xor((int)c10, 32);
      const unsigned c01x = __shfl_xor((int)c01, 32), c11x = __shfl_xor((int)c11, 32);
      const unsigned E = up ? c10x : c00, F = up ? c10 : c00x;
      const unsigned G = up ? c11x : c01, H = up ? c11 : c01x;
      const unsigned Ex = __shfl_xor((int)E, 16), Fx = __shfl_xor((int)F, 16);
      const unsigned Gx = __shfl_xor((int)G, 16), Hx = __shfl_xor((int)H, 16);
      union { unsigned w[4]; s16x8 v; } pw;
      pw.w[0] = subhi ? Fx : E;
      pw.w[1] = subhi ? Hx : G;
      pw.w[2] = subhi ? F  : Ex;
      pw.w[3] = subhi ? H  : Gx;
      pa[f] = pw.v;
    }
    #pragma unroll
    for (int db = 0; db < 4; ++db) {
      const s16x8 vf = *(const s16x8*)(Vg + ((size_t)(db*16 + qr))*kM + k0 + hi*8);
      acc[0][db] = __builtin_amdgcn_mfma_f32_16x16x32_bf16(pa[0], vf, acc[0][db], 0, 0, 0);
      acc[1][db] = __builtin_amdgcn_mfma_f32_16x16x32_bf16(pa[1], vf, acc[1][db], 0, 0, 0);
    }
  };

  loadK(kA, 0);
  qk(kA, sA);
  loadK(kB, 1);
  for (int kc = 0; kc < 16; kc += 2) {
    qk(kB, sB);
    if (kc + 2 < 16) loadK(kA, kc + 2);
    smpv(sA, kc);
    if (kc + 2 < 16) qk(kA, sA);
    if (kc + 3 < 16) loadK(kB, kc + 3);
    smpv(sB, kc + 1);
  }

  #pragma unroll
  for (int f = 0; f < 2; ++f) {
    float lf = l[f];
    lf += __shfl_xor(lf, 16); lf += __shfl_xor(lf, 32);
    const float li = 1.f/lf;
    const float l0 = __shfl(li, hi*4+0), l1 = __shfl(li, hi*4+1);
    const float l2 = __shfl(li, hi*4+2), l3 = __shfl(li, hi*4+3);
    #pragma unroll
    for (int db = 0; db < 4; ++db) {
      const size_t base = ((size_t)(bn*kM + q0 + f*16 + hi*4))*kD + h*kHD + db*16 + qr;
      ctx[base + 0*kD] = f2b(acc[f][db][0]*l0);
      ctx[base + 1*kD] = f2b(acc[f][db][1]*l1);
      ctx[base + 2*kD] = f2b(acc[f][db][2]*l2);
      ctx[base + 3*kD] = f2b(acc[f][db][3]*l3);
    }
  }
}

__device__ __forceinline__ void rope4(const f32x4 x, const f32x4 e0, const f32x4 e1, float o[4])
{
  o[0] = x[0]*e0[0] - x[1]*e1[0];
  o[1] = x[1]*e0[1] + x[0]*e1[1];
  o[2] = x[2]*e0[2] - x[3]*e1[2];
  o[3] = x[3]*e0[3] + x[2]*e1[3];
}

// ---------------------------------------------------------------------------
// FAT kernel: blocks [0,480) = s2s attention (64 q-rows/wave: 4 fragments
// sharing all K/V loads); blocks [480, 480+6144) = t2t attention.
// ---------------------------------------------------------------------------
__global__ __launch_bounds__(256) void attn_comb_k(
    const float* __restrict__ Qraw, const u16* __restrict__ Kb,
    const u16* __restrict__ Vt, const float* __restrict__ qenc,
    u16* __restrict__ ctx5, const u16* __restrict__ qkvU,
    u16* __restrict__ ctxU)
{
  if (blockIdx.x >= 480) {
    // ---- t2t ----
    const int wid = (blockIdx.x - 480)*4 + ((int)threadIdx.x >> 6);
    const int lane = threadIdx.x & 63;
    const int mm2 = wid & 511;
    const int t = wid >> 9;
    const int nq = t % kN;
    const int bh2 = t / kN;
    const int h2 = bh2 & 3, b2 = bh2 >> 2;
    const u16* pb[kN];
    #pragma unroll
    for (int nk = 0; nk < kN; ++nk)
      pb[nk] = qkvU + ((size_t)(b2*kN+nk)*kM + mm2)*768 + h2*192;
    const float qc = b2f(pb[nq][lane*3]);
    float sim[kN];
    #pragma unroll
    for (int nk = 0; nk < kN; ++nk)
      sim[nk] = wred_sum(qc * b2f(pb[nk][lane*3+1])) * 0.125f;
    float mx = sim[0];
    #pragma unroll
    for (int nk = 1; nk < kN; ++nk) mx = fmaxf(mx, sim[nk]);
    float p[kN], s = 0.f;
    #pragma unroll
    for (int nk = 0; nk < kN; ++nk) { p[nk] = expf(sim[nk]-mx); s += p[nk]; }
    const float inv = 1.f/s;
    float o = 0.f;
    #pragma unroll
    for (int nk = 0; nk < kN; ++nk) o = fmaf(p[nk], b2f(pb[nk][lane*3+2]), o);
    ctxU[((size_t)(b2*kN+nq)*kM + mm2)*kD + h2*kHD + lane] = f2b(o*inv);
    return;
  }
  // ---- s2s: 4 fragments (64 q-rows) per wave ----
  const int w = threadIdx.x >> 6, lane = threadIdx.x & 63;
  const int bij = (blockIdx.x & 7)*60 + (blockIdx.x >> 3);  // 480; chunk == bh
  const int bh = bij / 60;
  const int rest = bij % 60;
  const int col = rest / 10;
  const int rem = rest % 10;
  const int qblk = rem / 5, split = rem % 5;
  const int q0 = qblk*256 + w*64;
  const int qr = lane & 15, hi = lane >> 4;
  const bool subhi = (hi & 1), up = (hi >= 2);

  const int e  = split*6 + col;
  const int iv = e/5;
  const int j0 = e%5;
  const int jv = j0 + (j0 >= iv ? 1 : 0);

  s16x8 qf0[4], qf1[4];
  #pragma unroll
  for (int f = 0; f < 4; ++f) {
    const float* qp = Qraw + ((size_t)(bh*kN + jv)*kM + q0 + f*16 + qr)*kHD + hi*8;
    const float* ep = qenc + ((size_t)(iv*kN + jv))*kHD + hi*8;
    union { u16 u[8]; s16x8 v; } A, B;
    float o[4];
    rope4(*(const f32x4*)(qp),   *(const f32x4*)(ep),   *(const f32x4*)(ep+kQEncSlab), o);
    #pragma unroll
    for (int j = 0; j < 4; ++j) A.u[j] = f2b(o[j]*0.125f);
    rope4(*(const f32x4*)(qp+4), *(const f32x4*)(ep+4), *(const f32x4*)(ep+kQEncSlab+4), o);
    #pragma unroll
    for (int j = 0; j < 4; ++j) A.u[4+j] = f2b(o[j]*0.125f);
    rope4(*(const f32x4*)(qp+32), *(const f32x4*)(ep+32), *(const f32x4*)(ep+kQEncSlab+32), o);
    #pragma unroll
    for (int j = 0; j < 4; ++j) B.u[j] = f2b(o[j]*0.125f);
    rope4(*(const f32x4*)(qp+36), *(const f32x4*)(ep+36), *(const f32x4*)(ep+kQEncSlab+36), o);
    #pragma unroll
    for (int j = 0; j < 4; ++j) B.u[4+j] = f2b(o[j]*0.125f);
    qf0[f] = A.v; qf1[f] = B.v;
  }

  const int g2 = bh*kN + iv;
  const u16* Kg = Kb + (size_t)g2*kM*kHD;
  const u16* Vg = Vt + (size_t)g2*kHD*kM;
  f32x4 acc[4][4] = {};
  float m[4] = {-1e30f, -1e30f, -1e30f, -1e30f}, l[4] = {0.f, 0.f, 0.f, 0.f};

  for (int kc = 0; kc < 16; ++kc) {
    const int k0 = kc*32;
    s16x8 a0[2], a1[2];
    #pragma unroll
    for (int t = 0; t < 2; ++t) {
      const u16* kp = Kg + ((size_t)(k0 + t*16 + qr))*kHD + hi*8;
      a0[t] = *(const s16x8*)(kp);
      a1[t] = *(const s16x8*)(kp + 32);
    }
    s16x8 pa[4];
    #pragma unroll
    for (int f = 0; f < 4; ++f) {
      f32x4 st[2];
      #pragma unroll
      for (int t = 0; t < 2; ++t) {
        f32x4 z = {0.f, 0.f, 0.f, 0.f};
        z = __builtin_amdgcn_mfma_f32_16x16x32_bf16(a0[t], qf0[f], z, 0, 0, 0);
        z = __builtin_amdgcn_mfma_f32_16x16x32_bf16(a1[t], qf1[f], z, 0, 0, 0);
        st[t] = z;
      }
      float mloc = fmaxf(fmaxf(fmaxf(st[0][0], st[0][1]), fmaxf(st[0][2], st[0][3])),
                         fmaxf(fmaxf(st[1][0], st[1][1]), fmaxf(st[1][2], st[1][3])));
      if (!__all(mloc - m[f] <= 8.f)) {
        mloc = fmaxf(mloc, __shfl_xor(mloc, 16));
        mloc = fmaxf(mloc, __shfl_xor(mloc, 32));
        const float mn = fmaxf(m[f], mloc);
        const float r = exp2f((m[f] - mn)*kL2E);
        m[f] = mn;
        l[f] *= r;
        const float rr0 = __shfl(r, hi*4+0), rr1 = __shfl(r, hi*4+1);
        const float rr2 = __shfl(r, hi*4+2), rr3 = __shfl(r, hi*4+3);
        #pragma unroll
        for (int db = 0; db < 4; ++db) {
          acc[f][db][0] *= rr0; acc[f][db][1] *= rr1;
          acc[f][db][2] *= rr2; acc[f][db][3] *= rr3;
        }
      }
      float p[8], ls = 0.f;
      #pragma unroll
      for (int t = 0; t < 2; ++t)
        #pragma unroll
        for (int j = 0; j < 4; ++j) {
          const float pv = exp2f((st[t][j] - m[f])*kL2E);
          p[t*4+j] = pv; ls += pv;
        }
      l[f] += ls;
      const unsigned c00 = pk2(p[0], p[1]);
      const unsigned c01 = pk2(p[2], p[3]);
      const unsigned c10 = pk2(p[4], p[5]);
      const unsigned c11 = pk2(p[6], p[7]);
      const unsigned c00x = __shfl_xor((int)c00, 32), c10x = __shfl_xor((int)c10, 32);
      const unsigned c01x = __shfl_xor((int)c01, 32), c11x = __shfl_xor((int)c11, 32);
      const unsigned E = up ? c10x : c00, F = up ? c10 : c00x;
      const unsigned G = up ? c11x : c01, H = up ? c11 : c01x;
      const unsigned Ex = __shfl_xor((int)E, 16), Fx = __shfl_xor((int)F, 16);
      const unsigned Gx = __shfl_xor((int)G, 16), Hx = __shfl_xor((int)H, 16);
      union { unsigned w[4]; s16x8 v; } pw;
      pw.w[0] = subhi ? Fx : E;
      pw.w[1] = subhi ? Hx : G;
      pw.w[2] = subhi ? F  : Ex;
      pw.w[3] = subhi ? H  : Gx;
      pa[f] = pw.v;
    }
    #pragma unroll
    for (int db = 0; db < 4; ++db) {
      const s16x8 vf = *(const s16x8*)(Vg + ((size_t)(db*16 + qr))*kM + k0 + hi*8);
      #pragma unroll
      for (int f = 0; f < 4; ++f)
        acc[f][db] = __builtin_amdgcn_mfma_f32_16x16x32_bf16(pa[f], vf, acc[f][db], 0, 0, 0);
    }
  }

  const int b = bh >> 2, h = bh & 3;
  u16* outp = ctx5 + (size_t)split*kTOK;
  #pragma unroll
  for (int f = 0; f < 4; ++f) {
    float lf = l[f];
    lf += __shfl_xor(lf, 16); lf += __shfl_xor(lf, 32);
    const float li = 0.2f/lf;
    const float l0 = __shfl(li, hi*4+0), l1 = __shfl(li, hi*4+1);
    const float l2 = __shfl(li, hi*4+2), l3 = __shfl(li, hi*4+3);
    #pragma unroll
    for (int db = 0; db < 4; ++db) {
      const size_t base = ((size_t)((b*kN + col)*kM + q0 + f*16 + hi*4))*kD + h*kHD + db*16 + qr;
      outp[base + 0*kD] = f2b(acc[f][db][0]*l0);
      outp[base + 1*kD] = f2b(acc[f][db][1]*l1);
      outp[base + 2*kD] = f2b(acc[f][db][2]*l2);
      outp[base + 3*kD] = f2b(acc[f][db][3]*l3);
    }
  }
}

__global__ __launch_bounds__(256) void sum5_k(const u16* __restrict__ c5,
                                              u16* __restrict__ outU)
{
  const size_t i4 = ((size_t)blockIdx.x*256 + threadIdx.x)*4;
  float s0=0.f, s1=0.f, s2=0.f, s3=0.f;
  #pragma unroll
  for (int sp = 0; sp < 5; ++sp) {
    uint2 d = *(const uint2*)(c5 + sp*kTOK + i4);
    s0 += b2f((u16)(d.x & 0xffff)); s1 += b2f((u16)(d.x >> 16));
    s2 += b2f((u16)(d.y & 0xffff)); s3 += b2f((u16)(d.y >> 16));
  }
  union { u16 u[4]; uint2 d; } o;
  o.u[0]=f2b(s0); o.u[1]=f2b(s1); o.u[2]=f2b(s2); o.u[3]=f2b(s3);
  *(uint2*)(outU + i4) = o.d;
}

// LayerNorm(512) + exact GELU: wave per row, bf16 in/out, no LDS.
__global__ __launch_bounds__(256) void lngelu_k(
    const u16* __restrict__ x, u16* __restrict__ y,
    const float* __restrict__ g0, const float* __restrict__ b0,
    const float* __restrict__ g1, const float* __restrict__ b1, int Mh)
{
  const int w = threadIdx.x >> 6, lane = threadIdx.x & 63;
  const int row = blockIdx.x*4 + w;
  const float* g = (row < Mh) ? g0 : g1;
  const float* bb = (row < Mh) ? b0 : b1;
  const int o8 = lane*8;
  union { u16 u[8]; s16x8 v; } xv;
  xv.v = *(const s16x8*)(x + (size_t)row*512 + o8);
  float vf[8];
  float s1 = 0.f, s2 = 0.f;
  #pragma unroll
  for (int j = 0; j < 8; ++j) {
    vf[j] = b2f(xv.u[j]);
    s1 += vf[j]; s2 += vf[j]*vf[j];
  }
  s1 = wred_sum(s1); s2 = wred_sum(s2);
  const float mean = s1 * (1.f/512.f);
  const float ms   = s2 * (1.f/512.f);
  const float rs = rsqrtf(ms - mean*mean + 1e-5f);
  f32x4 gv0 = *(const f32x4*)(g + o8),  gv1 = *(const f32x4*)(g + o8 + 4);
  f32x4 bv0 = *(const f32x4*)(bb + o8), bv1 = *(const f32x4*)(bb + o8 + 4);
  union { u16 u[8]; s16x8 v; } ov;
  #pragma unroll
  for (int j = 0; j < 8; ++j) {
    const float gj = (j < 4) ? gv0[j] : gv1[j-4];
    const float bj = (j < 4) ? bv0[j] : bv1[j-4];
    const float yv = (vf[j]-mean)*rs*gj + bj;
    ov.u[j] = f2b(0.5f*yv*(1.f+erff(yv*0.70710678118654752f)));
  }
  *(s16x8*)(y + (size_t)row*512 + o8) = ov.v;
}

__global__ void conf_dot_k(const float* __restrict__ tmp, const float* __restrict__ w2,
                           const float* __restrict__ b2, float* __restrict__ out)
{
  const int w = threadIdx.x >> 6, lane = threadIdx.x & 63;
  const int row = blockIdx.x*4 + w;
  const float* t = tmp + (size_t)row*kD;
  float s = 0.f;
  #pragma unroll
  for (int j=0;j<4;++j) s = fmaf(t[lane+j*64], w2[lane+j*64], s);
  s = wred_sum(s);
  if (lane == 0) out[row] = s + b2[0];
}

// ---------------------------------------------------------------------------
extern "C" void kernel_launch(void* const* d_in, const int* in_sizes, int n_in,
                              void* d_out, int out_size, void* d_ws, size_t ws_size,
                              hipStream_t stream)
{
  auto F = [&](int i){ return (const float*)d_in[i]; };
  const float* t_desc = F(0);
  const float* s_desc = F(1);
  const float* t_enc  = F(2);
  const float* s_enc  = F(3);
  const float* q_enc  = F(4);
  const float* k_enc  = F(5);

  // ---- workspace map ----
  char* base = (char*)d_ws;
  float* xts = (float*)base;                     // 12288x256 f32 (xt|xs)
  float* xt = xts;
  float* xs = xts + kTOK;
  char* R1  = base + 2*kTOK*sizeof(float);       // 25.17 MB multi-use
  char* CTX = R1 + 4*kTOK*sizeof(float);         // 6.29 MB
  char* MSG = CTX + 2*kTOK*sizeof(u16);          // 6.29 MB
  u16* Qb16 = (u16*)(MSG + kTOK*sizeof(float));
  u16* Kb16 = Qb16 + 2*kTOK;
  u16* Vt16 = Kb16 + 2*kTOK;
  u16* wsW  = Vt16 + 2*kTOK;
  // aliases
  u16*   qkvU  = (u16*)R1;                       // 12288x768 bf16
  u16*   yH    = (u16*)R1;                       // 12288x512 bf16 (f1 out)
  u16*   ctx5  = qkvU + (size_t)kRowsH*768;      // 5 x 6144x256 bf16 (after t-half qkv)
  float* Wtmp  = (float*)R1;                     // 4 x 256x512 f32 (prep-time only)
  u16*   ctxU  = (u16*)CTX;                      // 12288x256
  float* Qs2s  = (float*)MSG;                    // 48x512x64 f32
  float* confb = (float*)MSG;                    // 6144x256 f32
  u16*   yU    = (u16*)CTX;                      // 12288x512 (spans CTX+MSG)

  float* out_t2s2 = (float*)d_out;
  float* out_conf = (float*)d_out + 2*kTOK;

  // ---- weight cast table (tiled Bs-image layout, W' fusion) ----
  WtTable tab;
  int nd = 0, total_tiles = 0;
  size_t woff = 0;
  const u16* wp[18];
  auto addw = [&](int idx, const float* W2, int K, int N){
    u16* dst = wsW + woff;
    tab.d[nd] = { F(idx), W2, dst, K, N, (N>>7)*(K>>5) };
    total_tiles += tab.d[nd].ntiles;
    wp[nd] = dst;
    woff += (size_t)K*N;
    ++nd;
    return nd-1;
  };
  const int W_SA_QKV = addw(6,  nullptr, 256, 768);
  const int W_SA_F1  = addw(10, Wtmp + 0*131072, 512, 512);
  const int W_SA_F2  = addw(14, nullptr, 512, 256);
  const int W_SS_QKV = addw(16, nullptr, 256, 768);
  const int W_SS_F1  = addw(20, Wtmp + 1*131072, 512, 512);
  const int W_SS_F2  = addw(24, nullptr, 512, 256);
  const int W_TT_QKV = addw(26, nullptr, 256, 768);
  const int W_TT_F1  = addw(30, Wtmp + 2*131072, 512, 512);
  const int W_TT_F2  = addw(34, nullptr, 512, 256);
  const int W_CA_Q   = addw(36, nullptr, 256, 256);  // contiguous with W_CA_KV
  const int W_CA_KV  = addw(38, nullptr, 256, 512);
  const int W_CA_F1  = addw(42, Wtmp + 3*131072, 512, 512);
  const int W_CA_F2  = addw(46, nullptr, 512, 256);
  const int W_CF_1   = addw(48, nullptr, 256, 256);
  (void)W_CA_KV;
  float* b1p = (float*)(wsW + woff);             // 4 x 512 f32 fused biases

  FuseArgs fa;
  fa.Wout[0]=F(8);  fa.Wout[1]=F(18); fa.Wout[2]=F(28); fa.Wout[3]=F(40);
  fa.W1[0]=F(10);   fa.W1[1]=F(20);   fa.W1[2]=F(30);   fa.W1[3]=F(42);
  fa.bout[0]=F(9);  fa.bout[1]=F(19); fa.bout[2]=F(29); fa.bout[3]=F(41);
  fa.b1[0]=F(11);   fa.b1[1]=F(21);   fa.b1[2]=F(31);   fa.b1[3]=F(43);
  fa.Wtmp = Wtmp; fa.b1p = b1p;
  wfuse_k<<<136, 256, 0, stream>>>(fa);
  wtcast_k<<<total_tiles, 256, 0, stream>>>(tab);

  // mmad launchers (dual row-segment, 12288 rows)
  auto mm_f32_to_b16 = [&](const float* a1a, const float* a1b, int wa, int wb2,
                           const float* ba, const float* bb2, u16* c, int N_, int K_){
    dim3 grid(N_/128, kRows/128);
    mmad_k<false,false,true><<<grid,256,0,stream>>>(a1a, a1b, nullptr, nullptr, K_,
        wp[wa], wp[wb2], ba, bb2, ba, bb2, N_, nullptr, nullptr, c, N_, K_, kRowsH, 0);
  };
  // fused f1: A = concat(x f32, ctx bf16), W = [W1_top; W'], bias = b1' -> bf16
  auto mm_f1 = [&](const float* a1a, const float* a1b, const u16* a2a, const u16* a2b,
                   int wa, int wb2, const float* ba, const float* bb2, u16* c){
    dim3 grid(512/128, kRows/128);
    mmad_k<false,true,true><<<grid,256,0,stream>>>(a1a, a1b, a2a, a2b, 256,
        wp[wa], wp[wb2], ba, bb2, ba, bb2, 512, nullptr, nullptr, c, 512, 512, kRowsH, 0);
  };
  auto mm_f2 = [&](const u16* a1a, const u16* a1b, int wa, int wb2,
                   const float* ba, const float* bb2,
                   const float* ra, const float* rb, float* c){
    dim3 grid(256/128, kRows/128);
    mmad_k<true,false,false><<<grid,256,0,stream>>>(a1a, a1b, nullptr, nullptr, 512,
        wp[wa], wp[wb2], ba, bb2, ba, bb2, 256, ra, rb, c, 256, 512, kRowsH, 0);
  };

  // ================= SELF (t || s, shared sa weights) =================
  mm_f32_to_b16(t_desc, s_desc, W_SA_QKV, W_SA_QKV, F(7), F(7), qkvU, 768, 256);
  prep_self_k<<<kGrp*8, 256, 0, stream>>>(qkvU, t_enc, s_enc, Qb16, Kb16, Vt16);
  attn_mm_k<0><<<384, 256, 0, stream>>>(Qb16, Kb16, Vt16, ctxU);
  mm_f1(t_desc, s_desc, ctxU, ctxU + kTOK, W_SA_F1, W_SA_F1, b1p+0*512, b1p+0*512, yH);
  lngelu_k<<<kRows/4, 256, 0, stream>>>(yH, yU, F(12), F(13), F(12), F(13), kRowsH);
  mm_f2(yU, yU + (size_t)kRowsH*512, W_SA_F2, W_SA_F2, F(15), F(15), t_desc, s_desc, xts);

  // ================= TT (t) || SS (s) =================
  mm_f32_to_b16(xt, xs, W_TT_QKV, W_SS_QKV, F(27), F(17), qkvU, 768, 256);
  prep_s2s_k<<<kGrpH*8, 256, 0, stream>>>(qkvU, k_enc, Qs2s, Kb16, Vt16);
  attn_comb_k<<<480 + 6144, 256, 0, stream>>>(Qs2s, Kb16, Vt16, q_enc, ctx5, qkvU, ctxU);
  sum5_k<<<(int)(kTOK/1024), 256, 0, stream>>>(ctx5, ctxU + kTOK);
  mm_f1(xt, xs, ctxU, ctxU + kTOK, W_TT_F1, W_SS_F1, b1p+2*512, b1p+1*512, yH);
  lngelu_k<<<kRows/4, 256, 0, stream>>>(yH, yU, F(32), F(33), F(22), F(23), kRowsH);
  mm_f2(yU, yU + (size_t)kRowsH*512, W_TT_F2, W_SS_F2, F(35), F(25), xt, xs, xts);

  // ================= CONF (from xs post-s2s) =================
  {
    dim3 grid(2, kRowsH/128);
    mmad_k<false,false,false><<<grid,256,0,stream>>>(xs, xs, nullptr, nullptr, 256,
        wp[W_CF_1], wp[W_CF_1], F(49), F(49), F(49), F(49), 256,
        nullptr, nullptr, confb, 256, 256, kRowsH, 1);
  }
  conf_dot_k<<<kRowsH/4, 256, 0, stream>>>(confb, F(50), F(51), out_conf);

  // ================= CROSS (merged q+kv GEMM) =================
  {
    dim3 grid(768/128, kRows/128);
    mmad_k<false,false,true><<<grid,256,0,stream>>>(xt, xs, nullptr, nullptr, 256,
        wp[W_CA_Q], wp[W_CA_Q], F(37), F(37), F(39), F(39), 256,
        nullptr, nullptr, qkvU, 768, 256, kRowsH, 0);
  }
  prep_cross_k<<<kGrp*8, 256, 0, stream>>>(qkvU, Kb16, Vt16);
  attn_mm_k<1><<<384, 256, 0, stream>>>(qkvU, Kb16, Vt16, ctxU);
  mm_f1(xt, xs, ctxU, ctxU + kTOK, W_CA_F1, W_CA_F1, b1p+3*512, b1p+3*512, yH);
  lngelu_k<<<kRows/4, 256, 0, stream>>>(yH, yU, F(44), F(45), F(44), F(45), kRowsH);
  mm_f2(yU, yU + (size_t)kRowsH*512, W_CA_F2, W_CA_F2, F(47), F(47), xt, xs, out_t2s2);
}